// Round 5
// baseline (523.730 us; speedup 1.0000x reference)
//
#include <hip/hip_runtime.h>

// Problem constants
#define BQ 8
#define CQ 16
#define LQ 2048
#define NQ 2048
#define NPS 128      // nperseg
#define STEPQ 64     // step (50% overlap)
#define SQ 31        // segments per series
#define FQ 65        // rfft bins
#define KQ 32        // nref
#define EPSQ 1e-12f

// ---- workspace layout (bytes) ----
#define XSPEC_OFF  0ull                          // float2 [B][F][S][C] = 257920 float2 (2063360 B)
#define PXX_OFF    2063360ull                    // float [B][C][F] = 8320 floats
#define SCORES_OFF 2096640ull                    // float [B][C][N] = 262144 floats (ends 3145216)

// ---- shared memory layout (float offsets) ----
#define YLD 66
#define OFF_Y     0                              // float2[31*66] = 4092 floats (LD=66, b128-aligned)
#define OFF_PYY   4092                           // 65
#define OFF_RED   4157                           // 256
#define SMEM_FLOATS 4413                         // 17652 B -> 8 blocks/CU (wave-capped)

// 16th roots of unity for stage-1 radix-16 (compile-time indexed)
__device__ __constant__ const float COS16_[16] = {
    1.0f, 0.92387953251128675613f, 0.70710678118654752440f, 0.38268343236508977173f,
    0.0f, -0.38268343236508977173f, -0.70710678118654752440f, -0.92387953251128675613f,
    -1.0f, -0.92387953251128675613f, -0.70710678118654752440f, -0.38268343236508977173f,
    0.0f, 0.38268343236508977173f, 0.70710678118654752440f, 0.92387953251128675613f};
__device__ __constant__ const float SIN16_[16] = {
    0.0f, 0.38268343236508977173f, 0.70710678118654752440f, 0.92387953251128675613f,
    1.0f, 0.92387953251128675613f, 0.70710678118654752440f, 0.38268343236508977173f,
    0.0f, -0.38268343236508977173f, -0.70710678118654752440f, -0.92387953251128675613f,
    -1.0f, -0.38268343236508977173f, -0.70710678118654752440f, -0.92387953251128675613f};

// compile-time {cos(2pi j/16), -sin(2pi j/16)} pairs (j folded constant after unroll)
#define C16R(j) ((j)==0?1.0f:(j)==1?0.92387953251128675613f:(j)==2?0.70710678118654752440f:\
    (j)==3?0.38268343236508977173f:(j)==4?0.0f:(j)==5?-0.38268343236508977173f:\
    (j)==6?-0.70710678118654752440f:(j)==7?-0.92387953251128675613f:(j)==8?-1.0f:\
    (j)==9?-0.92387953251128675613f:(j)==10?-0.70710678118654752440f:(j)==11?-0.38268343236508977173f:\
    (j)==12?0.0f:(j)==13?0.38268343236508977173f:(j)==14?0.70710678118654752440f:0.92387953251128675613f)
#define C16I(j) (-((j)==0?0.0f:(j)==1?0.38268343236508977173f:(j)==2?0.70710678118654752440f:\
    (j)==3?0.92387953251128675613f:(j)==4?1.0f:(j)==5?0.92387953251128675613f:\
    (j)==6?0.70710678118654752440f:(j)==7?0.38268343236508977173f:(j)==8?0.0f:\
    (j)==9?-0.38268343236508977173f:(j)==10?-0.70710678118654752440f:(j)==11?-0.92387953251128675613f:\
    (j)==12?-1.0f:(j)==13?-0.92387953251128675613f:(j)==14?-0.70710678118654752440f:-0.38268343236508977173f))

// stage-A butterfly twiddles W8^{t1-4} for t1>=4, identity for t1<4
__device__ __constant__ const float WA_R[8] = {1.f, 1.f, 1.f, 1.f,
    1.f, 0.70710678118654752440f, 0.f, -0.70710678118654752440f};
__device__ __constant__ const float WA_I[8] = {0.f, 0.f, 0.f, 0.f,
    0.f, -0.70710678118654752440f, -1.f, -0.70710678118654752440f};
__device__ __constant__ const int BR3_[8] = {0, 4, 2, 6, 1, 5, 3, 7};

#define TWOPI_128 0.049087385212340519350978802863742f   // 2*pi/128

// ---- VOP3P packed-fp32 helpers ----
// complex X*conj(Y) accumulate, acc={pr,pi}, x={xr,xi}, y={yr,yi}:
// step1: lo += xr*yr       hi += xi*yr      (b broadcasts lo half = yr)
__device__ __forceinline__ float2 pk_cma1(float2 x, float2 y, float2 acc) {
    float2 d;
    asm("v_pk_fma_f32 %0, %1, %2, %3 op_sel:[0,0,0] op_sel_hi:[1,0,1]"
        : "=v"(d) : "v"(x), "v"(y), "v"(acc));
    return d;
}
// step2: lo += xi*yi       hi += -xr*yi     (a muxed {xi,xr}, neg_hi; b broadcasts hi = yi)
__device__ __forceinline__ float2 pk_cma2(float2 x, float2 y, float2 acc) {
    float2 d;
    asm("v_pk_fma_f32 %0, %1, %2, %3 op_sel:[1,1,0] op_sel_hi:[0,1,1] neg_hi:[1,0,0]"
        : "=v"(d) : "v"(x), "v"(y), "v"(acc));
    return d;
}
// stage-1 DFT: g += x_lo * {cos,-sin}  (a broadcasts lo half; b = SGPR-pair constant)
__device__ __forceinline__ float2 pk_dft_lo(float2 xp, float2 w, float2 g) {
    float2 d;
    asm("v_pk_fma_f32 %0, %1, %2, %3 op_sel:[0,0,0] op_sel_hi:[0,1,1]"
        : "=v"(d) : "v"(xp), "s"(w), "v"(g));
    return d;
}
// stage-1 DFT: g += x_hi * {cos,-sin}
__device__ __forceinline__ float2 pk_dft_hi(float2 xp, float2 w, float2 g) {
    float2 d;
    asm("v_pk_fma_f32 %0, %1, %2, %3 op_sel:[1,0,0] op_sel_hi:[1,1,1]"
        : "=v"(d) : "v"(xp), "s"(w), "v"(g));
    return d;
}

// Welch spectra of one length-2048 row into smem Y (float2 [31][YLD], cols 0..64).
// Stage 1: radix-16 per (s,t1) thread from global, mean via lane shuffles, window in regs,
//          DFT accumulation in packed fp32 (v_pk_fma_f32, twiddles in SGPR pairs).
// Stage 2: 8-point DIF DFT across the 8 t1-lanes via shfl_xor (no LDS intermediate).
__device__ __forceinline__ void welch_spectra(const float* __restrict__ grow,
                                              float* smem) {
    const int tid = threadIdx.x;
    float2* s_y = (float2*)(smem + OFF_Y);

    const bool act = tid < SQ * 8;
    const int s = tid >> 3, t1 = tid & 7;

    float x[16];
    float sum = 0.f;
    if (act) {
        const float* rp = grow + s * STEPQ + t1;
#pragma unroll
        for (int t2 = 0; t2 < 16; ++t2) x[t2] = rp[8 * t2];
#pragma unroll
        for (int t2 = 0; t2 < 16; ++t2) sum += x[t2];
    }
    // segment mean across the 8 t1-lanes (contiguous lanes, same wave)
    sum += __shfl_xor(sum, 1, 64);
    sum += __shfl_xor(sum, 2, 64);
    sum += __shfl_xor(sum, 4, 64);
    const float mean = sum * (1.0f / 128.0f);

    float2 G[9];
    if (act) {
        float2 xp[8];
#pragma unroll
        for (int t2 = 0; t2 < 16; ++t2) {
            const float a = (float)(t1 + 8 * t2) * TWOPI_128;
            x[t2] = (x[t2] - mean) * (0.5f - 0.5f * __cosf(a));
        }
#pragma unroll
        for (int j = 0; j < 8; ++j) xp[j] = make_float2(x[2 * j], x[2 * j + 1]);
#pragma unroll
        for (int m = 0; m < 9; ++m) {
            float2 g = make_float2(0.f, 0.f);
#pragma unroll
            for (int j = 0; j < 8; ++j) {
                {
                    const int i0 = (m * (2 * j)) & 15;
                    g = pk_dft_lo(xp[j], make_float2(C16R(i0), C16I(i0)), g);
                }
                {
                    const int i1 = (m * (2 * j + 1)) & 15;
                    g = pk_dft_hi(xp[j], make_float2(C16R(i1), C16I(i1)), g);
                }
            }
            G[m] = g;
        }
    }

    // per-lane butterfly constants
    const float s1 = (t1 & 4) ? -1.f : 1.f;
    const float s2 = (t1 & 2) ? -1.f : 1.f;
    const float s3 = (t1 & 1) ? -1.f : 1.f;
    const float war = WA_R[t1], wai = WA_I[t1];
    const bool q3 = (t1 & 3) == 3;
    const int kbase = 16 * BR3_[t1];

    // incremental H-twiddle rotation: w(m') = e^{-2pi i t1 m'/128}
    float cr, ci;
    __sincosf((float)t1 * TWOPI_128, &ci, &cr);   // ci=sin, cr=cos
    ci = -ci;
    float wr = 1.f, wi = 0.f;

    if (act) {
#pragma unroll
        for (int mp = 0; mp < 16; ++mp) {
            const int mm = (mp <= 8) ? mp : 16 - mp;
            const float sg = (mp <= 8) ? 1.f : -1.f;   // conj(G) for m'>8 (real input)
            const float gr = G[mm].x, gi = sg * G[mm].y;
            float hr = wr * gr - wi * gi;
            float hi = wr * gi + wi * gr;
            // stage A: xor 4, twiddle W8^{t1-4} on upper lanes
            float orr = __shfl_xor(hr, 4, 64), oi = __shfl_xor(hi, 4, 64);
            float vr = fmaf(s1, hr, orr), vi = fmaf(s1, hi, oi);
            hr = vr * war - vi * wai;
            hi = vr * wai + vi * war;
            // stage B: xor 2, twiddle -i on q==3 lanes
            orr = __shfl_xor(hr, 2, 64); oi = __shfl_xor(hi, 2, 64);
            vr = fmaf(s2, hr, orr); vi = fmaf(s2, hi, oi);
            hr = q3 ? vi : vr;
            hi = q3 ? -vr : vi;
            // stage C: xor 1
            orr = __shfl_xor(hr, 1, 64); oi = __shfl_xor(hi, 1, 64);
            vr = fmaf(s3, hr, orr); vi = fmaf(s3, hi, oi);
            const int k = mp + kbase;                 // lane t1 holds output j=br3(t1)
            if (k <= 64) s_y[s * YLD + k] = make_float2(vr, vi);
            // rotate twiddle
            const float nwr = wr * cr - wi * ci;
            wi = wr * ci + wi * cr;
            wr = nwr;
        }
    }
    __syncthreads();
}

// Target spectra: one block per (b,c). Writes Xspec [B][F][S][C] (float2) and Pxx [B][C][F].
__global__ __launch_bounds__(256) void k_xspec(const float* __restrict__ tgt,
                                               float2* __restrict__ xspec,
                                               float* __restrict__ pxx) {
    __shared__ float smem[SMEM_FLOATS];
    const int blk = blockIdx.x;            // b*16 + c
    const int b = blk >> 4, c = blk & 15;
    welch_spectra(tgt + (size_t)blk * LQ, smem);
    const float2* s_y = (const float2*)(smem + OFF_Y);
    const int tid = threadIdx.x;
    for (int i = tid; i < SQ * FQ; i += 256) {
        const int s2 = i / 65, k = i - 65 * s2;
        xspec[((size_t)b * FQ + k) * (SQ * CQ) + s2 * CQ + c] = s_y[s2 * YLD + k];
    }
    if (tid < FQ) {
        float a = 0.f;
        for (int s = 0; s < SQ; ++s) {
            const float2 y = s_y[s * YLD + tid];
            a += y.x * y.x + y.y * y.y;
        }
        pxx[(size_t)blk * FQ + tid] = a * (1.0f / (float)SQ);
    }
}

// Score: one block per (b,n). Y spectra, Pyy, coherence vs 16 channels (packed fp32).
__global__ __launch_bounds__(256) void k_score(const float* __restrict__ db,
                                               const float2* __restrict__ xspec,
                                               const float* __restrict__ pxx,
                                               float* __restrict__ scores) {
    __shared__ float smem[SMEM_FLOATS];
    const int blk = blockIdx.x;            // b*2048 + n
    const int b = blk >> 11, n = blk & 2047;
    welch_spectra(db + (size_t)blk * LQ, smem);
    float* s_pyy = smem + OFF_PYY;
    float* s_red = smem + OFF_RED;
    const int tid = threadIdx.x;

    if (tid < FQ) {
        float a = 0.f;
        for (int s = 0; s < SQ; ++s) {
            const float2 y = ((const float2*)(smem + OFF_Y))[s * YLD + tid];
            a += y.x * y.x + y.y * y.y;
        }
        s_pyy[tid] = a * (1.0f / (float)SQ);
    }
    __syncthreads();

    const int c = tid & 15, g = tid >> 4;
    const int f0 = 4 * g;
    const float2* xb = xspec + (size_t)b * (FQ * SQ * CQ) + c;
    const float*  px = pxx + ((size_t)b * CQ + c) * FQ;

    // main loop: bins f0..f0+3; bin 64 in a post-loop (g==0 only)
    float2 a0 = make_float2(0.f, 0.f), a1 = a0, a2 = a0, a3 = a0;   // {pr,pi}

    for (int s = 0; s < SQ; ++s) {
        const float4* yp = (const float4*)(smem + OFF_Y + (size_t)(s * YLD + f0) * 2);
        const float4 ya = yp[0];            // y[f0] (x,y), y[f0+1] (z,w)
        const float4 yb = yp[1];            // y[f0+2], y[f0+3]
        const float2 x0 = xb[((f0 + 0) * SQ + s) * CQ];
        const float2 x1 = xb[((f0 + 1) * SQ + s) * CQ];
        const float2 x2 = xb[((f0 + 2) * SQ + s) * CQ];
        const float2 x3 = xb[((f0 + 3) * SQ + s) * CQ];
        const float2 y0 = make_float2(ya.x, ya.y), y1 = make_float2(ya.z, ya.w);
        const float2 y2 = make_float2(yb.x, yb.y), y3 = make_float2(yb.z, yb.w);
        a0 = pk_cma1(x0, y0, a0);  a0 = pk_cma2(x0, y0, a0);
        a1 = pk_cma1(x1, y1, a1);  a1 = pk_cma2(x1, y1, a1);
        a2 = pk_cma1(x2, y2, a2);  a2 = pk_cma2(x2, y2, a2);
        a3 = pk_cma1(x3, y3, a3);  a3 = pk_cma2(x3, y3, a3);
    }
    const float invS2 = 1.0f / ((float)SQ * (float)SQ);
    float acc = 0.f;
    acc += ((a0.x * a0.x + a0.y * a0.y) * invS2) / (px[f0 + 0] * s_pyy[f0 + 0] + EPSQ);
    acc += ((a1.x * a1.x + a1.y * a1.y) * invS2) / (px[f0 + 1] * s_pyy[f0 + 1] + EPSQ);
    acc += ((a2.x * a2.x + a2.y * a2.y) * invS2) / (px[f0 + 2] * s_pyy[f0 + 2] + EPSQ);
    acc += ((a3.x * a3.x + a3.y * a3.y) * invS2) / (px[f0 + 3] * s_pyy[f0 + 3] + EPSQ);

    if (g == 0) {                            // bin 64 tail, 16 threads
        float2 a4 = make_float2(0.f, 0.f);
        for (int s = 0; s < SQ; ++s) {
            const float2 y4 = ((const float2*)(smem + OFF_Y))[s * YLD + 64];
            const float2 x4 = xb[(64 * SQ + s) * CQ];
            a4 = pk_cma1(x4, y4, a4);  a4 = pk_cma2(x4, y4, a4);
        }
        acc += ((a4.x * a4.x + a4.y * a4.y) * invS2) / (px[64] * s_pyy[64] + EPSQ);
    }

    s_red[tid] = acc;                       // tid = g*16 + c
    __syncthreads();
    if (tid < 16) {
        float a = 0.f;
#pragma unroll
        for (int gg = 0; gg < 16; ++gg) a += s_red[gg * 16 + tid];
        scores[((size_t)b * CQ + tid) * NQ + n] = a * (1.0f / (float)FQ);
    }
}

// Fused top-32 + gather per (b,c) row. jax.lax.top_k semantics (desc, ties->lowest idx).
__global__ __launch_bounds__(256) void k_topk_gather(const float* __restrict__ scores,
                                                     const float* __restrict__ db,
                                                     float* __restrict__ out) {
    __shared__ float sv[NQ];
    __shared__ float rv[4];
    __shared__ int   ri[4];
    __shared__ int   sel[KQ];
    const int blk = blockIdx.x, tid = threadIdx.x;
    const int b = blk >> 4;
    const float* row = scores + (size_t)blk * NQ;
    for (int i = tid; i < NQ; i += 256) sv[i] = row[i];
    __syncthreads();
    for (int k = 0; k < KQ; ++k) {
        float best = -3.402823466e38f;
        int bi = 0x7fffffff;
        for (int j = tid; j < NQ; j += 256) {
            const float v = sv[j];
            if (v > best) { best = v; bi = j; }   // ascending j: strict > keeps smallest idx
        }
#pragma unroll
        for (int off = 1; off < 64; off <<= 1) {
            const float ov = __shfl_xor(best, off, 64);
            const int   oi = __shfl_xor(bi, off, 64);
            if (ov > best || (ov == best && oi < bi)) { best = ov; bi = oi; }
        }
        if ((tid & 63) == 0) { rv[tid >> 6] = best; ri[tid >> 6] = bi; }
        __syncthreads();
        if (tid == 0) {
            float bv = rv[0]; int bj = ri[0];
#pragma unroll
            for (int w = 1; w < 4; ++w) {
                if (rv[w] > bv || (rv[w] == bv && ri[w] < bj)) { bv = rv[w]; bj = ri[w]; }
            }
            sel[k] = bj;
            sv[bj] = -3.402823466e38f;
        }
        __syncthreads();
    }
    // gather: copy 32 selected rows (8 KB each) via float4
    const float4* dbv = (const float4*)(db + (size_t)b * NQ * LQ);
    float4* outv = (float4*)(out + (size_t)blk * KQ * LQ);
    for (int r = 0; r < KQ; ++r) {
        const int idx = sel[r];
        const float4* src = dbv + (size_t)idx * (LQ / 4);
        float4* dst = outv + (size_t)r * (LQ / 4);
        dst[tid] = src[tid];
        dst[tid + 256] = src[tid + 256];
    }
}

extern "C" void kernel_launch(void* const* d_in, const int* in_sizes, int n_in,
                              void* d_out, int out_size, void* d_ws, size_t ws_size,
                              hipStream_t stream) {
    const float* tgt = (const float*)d_in[0];   // [8,16,2048]
    const float* db  = (const float*)d_in[1];   // [8,2048,2048]
    float* out = (float*)d_out;                 // [8,512,2048]
    char* ws = (char*)d_ws;

    float2* xspec  = (float2*)(ws + XSPEC_OFF);
    float*  pxx    = (float*)(ws + PXX_OFF);
    float*  scores = (float*)(ws + SCORES_OFF);

    hipLaunchKernelGGL(k_xspec,       dim3(BQ * CQ), dim3(256), 0, stream, tgt, xspec, pxx);
    hipLaunchKernelGGL(k_score,       dim3(BQ * NQ), dim3(256), 0, stream, db, xspec, pxx, scores);
    hipLaunchKernelGGL(k_topk_gather, dim3(BQ * CQ), dim3(256), 0, stream, scores, db, out);
}

// Round 6
// 456.775 us; speedup vs baseline: 1.1466x; 1.1466x over previous
//
#include <hip/hip_runtime.h>

// Problem constants
#define BQ 8
#define CQ 16
#define LQ 2048
#define NQ 2048
#define NPS 128      // nperseg
#define STEPQ 64     // step (50% overlap)
#define SQ 31        // segments per series
#define FQ 65        // rfft bins
#define KQ 32        // nref
#define EPSQ 1e-12f

// ---- workspace layout (bytes) ----
// xquad: float2 [B][16][S][C][4] = 253952 float2 (2031616 B)  -- bins 0..63 as quads
// xtail: float2 [B][S][C]        = 3968 float2  (31744 B)     -- bin 64
#define XQ_OFF     0ull
#define XTAIL_OFF  2031616ull
#define PXX_OFF    2063360ull                    // float [B][C][F] = 8320 floats
#define SCORES_OFF 2096640ull                    // float [B][C][N] = 262144 floats
#define TOPK_OFF   3145216ull                    // int [B][C][K] = 8192 ints (ends 3177984)

// ---- shared memory layout (float offsets) ----
#define YLD 66
#define OFF_Y     0                              // float2[31*66] = 4092 floats (LD=66, b128-aligned)
#define OFF_PYY   4092                           // 65
#define OFF_RED   4157                           // 256
#define SMEM_FLOATS 4413                         // 17652 B -> 8 blocks/CU (wave-capped)

// compile-time {cos(2pi j/16), -sin(2pi j/16)} pairs (j folded constant after unroll)
#define C16R(j) ((j)==0?1.0f:(j)==1?0.92387953251128675613f:(j)==2?0.70710678118654752440f:\
    (j)==3?0.38268343236508977173f:(j)==4?0.0f:(j)==5?-0.38268343236508977173f:\
    (j)==6?-0.70710678118654752440f:(j)==7?-0.92387953251128675613f:(j)==8?-1.0f:\
    (j)==9?-0.92387953251128675613f:(j)==10?-0.70710678118654752440f:(j)==11?-0.38268343236508977173f:\
    (j)==12?0.0f:(j)==13?0.38268343236508977173f:(j)==14?0.70710678118654752440f:0.92387953251128675613f)
#define C16I(j) (-((j)==0?0.0f:(j)==1?0.38268343236508977173f:(j)==2?0.70710678118654752440f:\
    (j)==3?0.92387953251128675613f:(j)==4?1.0f:(j)==5?0.92387953251128675613f:\
    (j)==6?0.70710678118654752440f:(j)==7?0.38268343236508977173f:(j)==8?0.0f:\
    (j)==9?-0.38268343236508977173f:(j)==10?-0.70710678118654752440f:(j)==11?-0.92387953251128675613f:\
    (j)==12?-1.0f:(j)==13?-0.92387953251128675613f:(j)==14?-0.70710678118654752440f:-0.38268343236508977173f))

// stage-A butterfly twiddles W8^{t1-4} for t1>=4, identity for t1<4
__device__ __constant__ const float WA_R[8] = {1.f, 1.f, 1.f, 1.f,
    1.f, 0.70710678118654752440f, 0.f, -0.70710678118654752440f};
__device__ __constant__ const float WA_I[8] = {0.f, 0.f, 0.f, 0.f,
    0.f, -0.70710678118654752440f, -1.f, -0.70710678118654752440f};
__device__ __constant__ const int BR3_[8] = {0, 4, 2, 6, 1, 5, 3, 7};

#define TWOPI_128 0.049087385212340519350978802863742f   // 2*pi/128

// ---- DPP lane-xor within quads/pairs (VALU pipe, not LDS) ----
__device__ __forceinline__ float dppx1(float v) {   // lane ^ 1: quad_perm [1,0,3,2] = 0xB1
    return __int_as_float(__builtin_amdgcn_update_dpp(0, __float_as_int(v), 0xB1, 0xF, 0xF, true));
}
__device__ __forceinline__ float dppx2(float v) {   // lane ^ 2: quad_perm [2,3,0,1] = 0x4E
    return __int_as_float(__builtin_amdgcn_update_dpp(0, __float_as_int(v), 0x4E, 0xF, 0xF, true));
}

// ---- VOP3P packed-fp32 helpers ----
// complex X*conj(Y) accumulate, acc={pr,pi}, x={xr,xi}, y={yr,yi}:
__device__ __forceinline__ float2 pk_cma1(float2 x, float2 y, float2 acc) {
    float2 d;
    asm("v_pk_fma_f32 %0, %1, %2, %3 op_sel:[0,0,0] op_sel_hi:[1,0,1]"
        : "=v"(d) : "v"(x), "v"(y), "v"(acc));
    return d;
}
__device__ __forceinline__ float2 pk_cma2(float2 x, float2 y, float2 acc) {
    float2 d;
    asm("v_pk_fma_f32 %0, %1, %2, %3 op_sel:[1,1,0] op_sel_hi:[0,1,1] neg_hi:[1,0,0]"
        : "=v"(d) : "v"(x), "v"(y), "v"(acc));
    return d;
}
// stage-1 DFT: g += x_lo * {cos,-sin}  (a broadcasts lo/hi half; b = SGPR-pair constant)
__device__ __forceinline__ float2 pk_dft_lo(float2 xp, float2 w, float2 g) {
    float2 d;
    asm("v_pk_fma_f32 %0, %1, %2, %3 op_sel:[0,0,0] op_sel_hi:[0,1,1]"
        : "=v"(d) : "v"(xp), "s"(w), "v"(g));
    return d;
}
__device__ __forceinline__ float2 pk_dft_hi(float2 xp, float2 w, float2 g) {
    float2 d;
    asm("v_pk_fma_f32 %0, %1, %2, %3 op_sel:[1,0,0] op_sel_hi:[1,1,1]"
        : "=v"(d) : "v"(xp), "s"(w), "v"(g));
    return d;
}

// Welch spectra of one length-2048 row into smem Y (float2 [31][YLD], cols 0..64).
__device__ __forceinline__ void welch_spectra(const float* __restrict__ grow,
                                              float* smem) {
    const int tid = threadIdx.x;
    float2* s_y = (float2*)(smem + OFF_Y);

    const bool act = tid < SQ * 8;
    const int s = tid >> 3, t1 = tid & 7;

    float x[16];
    float sum = 0.f;
    if (act) {
        const float* rp = grow + s * STEPQ + t1;
#pragma unroll
        for (int t2 = 0; t2 < 16; ++t2) x[t2] = rp[8 * t2];
#pragma unroll
        for (int t2 = 0; t2 < 16; ++t2) sum += x[t2];
    }
    // segment mean across the 8 t1-lanes (xor1/2 via DPP, xor4 via shfl)
    sum += dppx1(sum);
    sum += dppx2(sum);
    sum += __shfl_xor(sum, 4, 64);
    const float mean = sum * (1.0f / 128.0f);

    float2 G[9];
    if (act) {
        float2 xp[8];
#pragma unroll
        for (int t2 = 0; t2 < 16; ++t2) {
            const float a = (float)(t1 + 8 * t2) * TWOPI_128;
            x[t2] = (x[t2] - mean) * (0.5f - 0.5f * __cosf(a));
        }
#pragma unroll
        for (int j = 0; j < 8; ++j) xp[j] = make_float2(x[2 * j], x[2 * j + 1]);
#pragma unroll
        for (int m = 0; m < 9; ++m) {
            float2 g = make_float2(0.f, 0.f);
#pragma unroll
            for (int j = 0; j < 8; ++j) {
                {
                    const int i0 = (m * (2 * j)) & 15;
                    g = pk_dft_lo(xp[j], make_float2(C16R(i0), C16I(i0)), g);
                }
                {
                    const int i1 = (m * (2 * j + 1)) & 15;
                    g = pk_dft_hi(xp[j], make_float2(C16R(i1), C16I(i1)), g);
                }
            }
            G[m] = g;
        }
    }

    // per-lane butterfly constants
    const float s1 = (t1 & 4) ? -1.f : 1.f;
    const float s2 = (t1 & 2) ? -1.f : 1.f;
    const float s3 = (t1 & 1) ? -1.f : 1.f;
    const float war = WA_R[t1], wai = WA_I[t1];
    const bool q3 = (t1 & 3) == 3;
    const int kbase = 16 * BR3_[t1];

    // incremental H-twiddle rotation: w(m') = e^{-2pi i t1 m'/128}
    float cr, ci;
    __sincosf((float)t1 * TWOPI_128, &ci, &cr);   // ci=sin, cr=cos
    ci = -ci;
    float wr = 1.f, wi = 0.f;

    if (act) {
#pragma unroll
        for (int mp = 0; mp < 16; ++mp) {
            const int mm = (mp <= 8) ? mp : 16 - mp;
            const float sg = (mp <= 8) ? 1.f : -1.f;   // conj(G) for m'>8 (real input)
            const float gr = G[mm].x, gi = sg * G[mm].y;
            float hr = wr * gr - wi * gi;
            float hi = wr * gi + wi * gr;
            // stage A: xor 4 (shfl), twiddle W8^{t1-4} on upper lanes
            float orr = __shfl_xor(hr, 4, 64), oi = __shfl_xor(hi, 4, 64);
            float vr = fmaf(s1, hr, orr), vi = fmaf(s1, hi, oi);
            hr = vr * war - vi * wai;
            hi = vr * wai + vi * war;
            // stage B: xor 2 (DPP), twiddle -i on q==3 lanes
            orr = dppx2(hr); oi = dppx2(hi);
            vr = fmaf(s2, hr, orr); vi = fmaf(s2, hi, oi);
            hr = q3 ? vi : vr;
            hi = q3 ? -vr : vi;
            // stage C: xor 1 (DPP)
            orr = dppx1(hr); oi = dppx1(hi);
            vr = fmaf(s3, hr, orr); vi = fmaf(s3, hi, oi);
            const int k = mp + kbase;                 // lane t1 holds output j=br3(t1)
            if (k <= 64) s_y[s * YLD + k] = make_float2(vr, vi);
            // rotate twiddle
            const float nwr = wr * cr - wi * ci;
            wi = wr * ci + wi * cr;
            wr = nwr;
        }
    }
    __syncthreads();
}

// Target spectra: one block per (b,c). Writes xquad/xtail and Pxx [B][C][F].
__global__ __launch_bounds__(256) void k_xspec(const float* __restrict__ tgt,
                                               float2* __restrict__ xquad,
                                               float2* __restrict__ xtail,
                                               float* __restrict__ pxx) {
    __shared__ float smem[SMEM_FLOATS];
    const int blk = blockIdx.x;            // b*16 + c
    const int b = blk >> 4, c = blk & 15;
    welch_spectra(tgt + (size_t)blk * LQ, smem);
    const float2* s_y = (const float2*)(smem + OFF_Y);
    const int tid = threadIdx.x;
    for (int i = tid; i < SQ * FQ; i += 256) {
        const int s2 = i / 65, k = i - 65 * s2;
        const float2 v = s_y[s2 * YLD + k];
        if (k < 64) {
            const int q = k >> 2, j = k & 3;
            xquad[((((size_t)b * 16 + q) * SQ + s2) * CQ + c) * 4 + j] = v;
        } else {
            xtail[((size_t)b * SQ + s2) * CQ + c] = v;
        }
    }
    if (tid < FQ) {
        float a = 0.f;
        for (int s = 0; s < SQ; ++s) {
            const float2 y = s_y[s * YLD + tid];
            a += y.x * y.x + y.y * y.y;
        }
        pxx[(size_t)blk * FQ + tid] = a * (1.0f / (float)SQ);
    }
}

// Score: one block per (b,n). Y spectra, Pyy, coherence vs 16 channels (packed fp32).
__global__ __launch_bounds__(256) void k_score(const float* __restrict__ db,
                                               const float2* __restrict__ xquad,
                                               const float2* __restrict__ xtail,
                                               const float* __restrict__ pxx,
                                               float* __restrict__ scores) {
    __shared__ float smem[SMEM_FLOATS];
    const int blk = blockIdx.x;            // b*2048 + n
    const int b = blk >> 11, n = blk & 2047;
    welch_spectra(db + (size_t)blk * LQ, smem);
    float* s_pyy = smem + OFF_PYY;
    float* s_red = smem + OFF_RED;
    const int tid = threadIdx.x;

    if (tid < FQ) {
        float a = 0.f;
        for (int s = 0; s < SQ; ++s) {
            const float2 y = ((const float2*)(smem + OFF_Y))[s * YLD + tid];
            a += y.x * y.x + y.y * y.y;
        }
        s_pyy[tid] = a * (1.0f / (float)SQ);
    }
    __syncthreads();

    const int c = tid & 15, g = tid >> 4;
    const int f0 = 4 * g;
    // x quad pointer for (b, q=g, c): 2 float4 per (s,c); stride per s = 32 float4
    const float4* xp = (const float4*)xquad + (((size_t)(b * 16 + g) * SQ) * CQ + c) * 2;
    const float*  px = pxx + ((size_t)b * CQ + c) * FQ;

    float2 a0 = make_float2(0.f, 0.f), a1 = a0, a2 = a0, a3 = a0;   // {pr,pi}

    for (int s = 0; s < SQ; ++s) {
        const float4* yp = (const float4*)(smem + OFF_Y + (size_t)(s * YLD + f0) * 2);
        const float4 ya = yp[0];            // y[f0] (x,y), y[f0+1] (z,w)
        const float4 yb = yp[1];            // y[f0+2], y[f0+3]
        const float4 xa = xp[0];            // x[f0], x[f0+1]
        const float4 xb4 = xp[1];           // x[f0+2], x[f0+3]
        xp += 32;
        const float2 x0 = make_float2(xa.x, xa.y), x1 = make_float2(xa.z, xa.w);
        const float2 x2 = make_float2(xb4.x, xb4.y), x3 = make_float2(xb4.z, xb4.w);
        const float2 y0 = make_float2(ya.x, ya.y), y1 = make_float2(ya.z, ya.w);
        const float2 y2 = make_float2(yb.x, yb.y), y3 = make_float2(yb.z, yb.w);
        a0 = pk_cma1(x0, y0, a0);  a0 = pk_cma2(x0, y0, a0);
        a1 = pk_cma1(x1, y1, a1);  a1 = pk_cma2(x1, y1, a1);
        a2 = pk_cma1(x2, y2, a2);  a2 = pk_cma2(x2, y2, a2);
        a3 = pk_cma1(x3, y3, a3);  a3 = pk_cma2(x3, y3, a3);
    }
    const float invS2 = 1.0f / ((float)SQ * (float)SQ);
    float acc = 0.f;
    acc += ((a0.x * a0.x + a0.y * a0.y) * invS2) / (px[f0 + 0] * s_pyy[f0 + 0] + EPSQ);
    acc += ((a1.x * a1.x + a1.y * a1.y) * invS2) / (px[f0 + 1] * s_pyy[f0 + 1] + EPSQ);
    acc += ((a2.x * a2.x + a2.y * a2.y) * invS2) / (px[f0 + 2] * s_pyy[f0 + 2] + EPSQ);
    acc += ((a3.x * a3.x + a3.y * a3.y) * invS2) / (px[f0 + 3] * s_pyy[f0 + 3] + EPSQ);

    if (g == 0) {                            // bin 64 tail, 16 threads
        float2 a4 = make_float2(0.f, 0.f);
        const float2* xt = xtail + (size_t)b * SQ * CQ + c;
        for (int s = 0; s < SQ; ++s) {
            const float2 y4 = ((const float2*)(smem + OFF_Y))[s * YLD + 64];
            const float2 x4 = xt[s * CQ];
            a4 = pk_cma1(x4, y4, a4);  a4 = pk_cma2(x4, y4, a4);
        }
        acc += ((a4.x * a4.x + a4.y * a4.y) * invS2) / (px[64] * s_pyy[64] + EPSQ);
    }

    s_red[tid] = acc;                       // tid = g*16 + c
    __syncthreads();
    if (tid < 16) {
        float a = 0.f;
#pragma unroll
        for (int gg = 0; gg < 16; ++gg) a += s_red[gg * 16 + tid];
        scores[((size_t)b * CQ + tid) * NQ + n] = a * (1.0f / (float)FQ);
    }
}

// Top-32 per (b,c) row, jax.lax.top_k semantics (desc, ties->lowest idx).
__global__ __launch_bounds__(256) void k_topk(const float* __restrict__ scores,
                                              int* __restrict__ topk) {
    __shared__ float sv[NQ];
    __shared__ float rv[4];
    __shared__ int   ri[4];
    const int blk = blockIdx.x, tid = threadIdx.x;
    const float* row = scores + (size_t)blk * NQ;
    for (int i = tid; i < NQ; i += 256) sv[i] = row[i];
    __syncthreads();
    for (int k = 0; k < KQ; ++k) {
        float best = -3.402823466e38f;
        int bi = 0x7fffffff;
        for (int j = tid; j < NQ; j += 256) {
            const float v = sv[j];
            if (v > best) { best = v; bi = j; }   // ascending j: strict > keeps smallest idx
        }
#pragma unroll
        for (int off = 1; off < 64; off <<= 1) {
            const float ov = __shfl_xor(best, off, 64);
            const int   oi = __shfl_xor(bi, off, 64);
            if (ov > best || (ov == best && oi < bi)) { best = ov; bi = oi; }
        }
        if ((tid & 63) == 0) { rv[tid >> 6] = best; ri[tid >> 6] = bi; }
        __syncthreads();
        if (tid == 0) {
            float bv = rv[0]; int bj = ri[0];
#pragma unroll
            for (int w = 1; w < 4; ++w) {
                if (rv[w] > bv || (rv[w] == bv && ri[w] < bj)) { bv = rv[w]; bj = ri[w]; }
            }
            topk[blk * KQ + k] = bj;
            sv[bj] = -3.402823466e38f;
        }
        __syncthreads();
    }
}

// Gather: one block per output row (b, c*32+k) -> copy DB row (2048 floats) via float4.
__global__ __launch_bounds__(256) void k_gather(const float* __restrict__ db,
                                                const int* __restrict__ topk,
                                                float* __restrict__ out) {
    const int row = blockIdx.x;               // b*512 + c*32 + k
    const int b = row >> 9;
    const int idx = topk[row];
    const float4* src = (const float4*)(db + ((size_t)(b * NQ + idx)) * LQ);
    float4* dst = (float4*)(out + (size_t)row * LQ);
    const int tid = threadIdx.x;
    dst[tid] = src[tid];
    dst[tid + 256] = src[tid + 256];
}

extern "C" void kernel_launch(void* const* d_in, const int* in_sizes, int n_in,
                              void* d_out, int out_size, void* d_ws, size_t ws_size,
                              hipStream_t stream) {
    const float* tgt = (const float*)d_in[0];   // [8,16,2048]
    const float* db  = (const float*)d_in[1];   // [8,2048,2048]
    float* out = (float*)d_out;                 // [8,512,2048]
    char* ws = (char*)d_ws;

    float2* xquad  = (float2*)(ws + XQ_OFF);
    float2* xtail  = (float2*)(ws + XTAIL_OFF);
    float*  pxx    = (float*)(ws + PXX_OFF);
    float*  scores = (float*)(ws + SCORES_OFF);
    int*    topk   = (int*)(ws + TOPK_OFF);

    hipLaunchKernelGGL(k_xspec,  dim3(BQ * CQ),      dim3(256), 0, stream, tgt, xquad, xtail, pxx);
    hipLaunchKernelGGL(k_score,  dim3(BQ * NQ),      dim3(256), 0, stream, db, xquad, xtail, pxx, scores);
    hipLaunchKernelGGL(k_topk,   dim3(BQ * CQ),      dim3(256), 0, stream, scores, topk);
    hipLaunchKernelGGL(k_gather, dim3(BQ * CQ * KQ), dim3(256), 0, stream, db, topk, out);
}